// Round 15
// baseline (204.092 us; speedup 1.0000x reference)
//
#include <hip/hip_runtime.h>

// Problem constants
#define B_     4
#define CIN    256
#define NTOK   2304        // 48*48
#define HEADS  8
#define HD     64
#define SCALE  0.125f      // 1/sqrt(64)
#define LOG2E  1.44269504088896f
#define QSCALE (SCALE * LOG2E)     // fold softmax exp->exp2 conversion into q
#define PBIAS  4.0f                // static softmax normalizer, folded into acc init
#define QKV_ELEMS (HEADS * B_ * NTOK * HD)   // 4,718,592
#define HBSTRIDE 147456    // 2304*64 elems per (h,b)
#define WSZ    131072      // elems in one of Wq/Wk/Wv ([8][64][256]) and Wo ([256][512])

typedef _Float16 f16;
typedef _Float16 __attribute__((ext_vector_type(8))) h8v;   // MFMA A/B frag
typedef _Float16 __attribute__((ext_vector_type(4))) h4v;
typedef ushort   __attribute__((ext_vector_type(8))) us8;
typedef float    __attribute__((ext_vector_type(16))) f16v; // 32x32 MFMA acc

__device__ inline uint pk2(float a, float b) { // pack 2xf32 -> 2xf16 (RTZ)
    auto v = __builtin_amdgcn_cvt_pkrtz(a, b);
    return __builtin_bit_cast(uint, v);
}
#define EXP2(x) __builtin_amdgcn_exp2f(x)      // native v_exp_f32

// async global->LDS DMA, 16 B/lane, LDS dest = uniform base + lane*16
#define GLOAD_LDS(g, l) __builtin_amdgcn_global_load_lds( \
    (const __attribute__((address_space(1))) unsigned int*)(g), \
    (__attribute__((address_space(3))) unsigned int*)(l), 16, 0, 0)

// ---------------------------------------------------------------------------
// prep: fused castw + tcastf (data-independent; saves one launch).
// Blocks 0..511:   weights fp32 -> f16 (QSCALE folded into Wq).
// Blocks 512..1087: x fp32 [b][C][NTOK] -> xt f16 TRANSPOSED [b][n][C].
// ---------------------------------------------------------------------------
__global__ __launch_bounds__(256) void prep(
    const float* __restrict__ x,
    const float* __restrict__ Wq, const float* __restrict__ Wk,
    const float* __restrict__ Wv, const float* __restrict__ Wo,
    f16* __restrict__ wc, f16* __restrict__ woc, f16* __restrict__ xt)
{
    __shared__ float T[64][65];
    const int bid = blockIdx.x;
    const int tid = threadIdx.x;

    if (bid < 512) {                       // ---- castw path
        int e4 = (bid * 256 + tid) * 4;
        const float* src; f16* dst; float mult = 1.0f; int off;
        if (e4 < WSZ)          { src = Wq; off = e4;           dst = wc;           mult = QSCALE; }
        else if (e4 < 2 * WSZ) { src = Wk; off = e4 - WSZ;     dst = wc + WSZ; }
        else if (e4 < 3 * WSZ) { src = Wv; off = e4 - 2 * WSZ; dst = wc + 2 * WSZ; }
        else                   { src = Wo; off = e4 - 3 * WSZ; dst = woc; }
        float4 r = *(const float4*)(src + off);
        h4v hv;
        hv.x = (f16)(r.x * mult); hv.y = (f16)(r.y * mult);
        hv.z = (f16)(r.z * mult); hv.w = (f16)(r.w * mult);
        *(h4v*)(dst + off) = hv;
        return;
    }

    // ---- tcastf path
    const int r  = bid - 512;              // 0..575
    const int n0 = (r % 36) * 64;
    const int c0 = ((r / 36) % 4) * 64;
    const int b  = r / 144;
    const float* sb = x + ((size_t)b * CIN + c0) * NTOK;
    #pragma unroll
    for (int i = 0; i < 16; ++i) {
        int idx = tid + 256 * i;
        int rr = idx >> 6, ll = idx & 63;
        T[ll][rr] = sb[(size_t)rr * NTOK + n0 + ll];
    }
    __syncthreads();
    const size_t ob = ((size_t)b * NTOK + n0) * CIN + c0;
    #pragma unroll
    for (int i = 0; i < 4; ++i) {
        int idx = tid + 256 * i;
        int row = idx >> 4, c4 = (idx & 15) * 4;
        h4v v;
        v.x = (f16)T[row][c4 + 0]; v.y = (f16)T[row][c4 + 1];
        v.z = (f16)T[row][c4 + 2]; v.w = (f16)T[row][c4 + 3];
        *(h4v*)(xt + ob + (size_t)row * CIN + c4) = v;
    }
}

// ---------------------------------------------------------------------------
// proj_mfma: q/k/v projections, single-f16 MFMA. 32 KiB single-buffered
// LDS (5 blocks/CU), conservative compute->B->stage->B schedule (round 13;
// neutral vs dbuf, kept for the residency headroom). Block 128 (2 waves):
// wave0 DMAs W, wave1 DMAs X. Grid (36, 24, 4).
// ---------------------------------------------------------------------------
__global__ __launch_bounds__(128) void proj_mfma(
    const f16* __restrict__ wc, const f16* __restrict__ xt,
    f16* __restrict__ qh, f16* __restrict__ kh, f16* __restrict__ vth)
{
    const int ntile = blockIdx.x;
    const int hp    = blockIdx.y;
    const int b     = blockIdx.z;
    const int p     = hp >> 3, h = hp & 7;
    const int hb    = h * 4 + b;
    const f16* Wp = wc + ((size_t)p * 8 + h) * (HD * CIN);

    // swizzled: physical slot c of row r holds logical col-slot c ^ (r&7)
    __shared__ __align__(16) f16 Ws[64][64], Xs[64][64];   // 32 KiB

    const int tid = threadIdx.x;
    const int w = tid >> 6, lane = tid & 63;
    const int lm = lane & 31, lh = lane >> 5;
    const int n_loc  = w * 32 + lm;
    const int n_glob = ntile * 64 + n_loc;

    const f16* xb = xt + ((size_t)b * NTOK + ntile * 64) * CIN;

    auto stage = [&](int c0) {
        const f16* src = (w == 0) ? Wp : xb;
        f16* dst = (w == 0) ? &Ws[0][0] : &Xs[0][0];
        #pragma unroll
        for (int i = 0; i < 8; ++i) {
            int g = i * 64 + lane; int row = g >> 3; int c = (g & 7) ^ (row & 7);
            GLOAD_LDS(src + (size_t)row * CIN + c0 + c * 8, dst + i * 512);
        }
    };

    f16v o0, o1;
    #pragma unroll
    for (int i = 0; i < 16; ++i) { o0[i] = 0.f; o1[i] = 0.f; }

    stage(0);
    __syncthreads();                       // drain chunk 0
    for (int c0 = 0; c0 < CIN; c0 += 64) {
        #pragma unroll
        for (int s = 0; s < 4; ++s) {
            const int pp = ((2 * s + lh) ^ (lm & 7)) * 8;   // (lm+32)&7 == lm&7
            h8v a0 = *(const h8v*)&Ws[lm][pp];
            h8v a1 = *(const h8v*)&Ws[lm + 32][pp];
            h8v bh = *(const h8v*)&Xs[n_loc][pp];           // n_loc&7 == lm&7
            o0 = __builtin_amdgcn_mfma_f32_32x32x16_f16(a0, bh, o0, 0, 0, 0);
            o1 = __builtin_amdgcn_mfma_f32_32x32x16_f16(a1, bh, o1, 0, 0, 0);
        }
        if (c0 + 64 < CIN) {
            __syncthreads();               // all reads of this chunk done
            stage(c0 + 64);
            __syncthreads();               // drain next chunk
        }
    }

    const size_t hboff = (size_t)hb * HBSTRIDE;
    if (p < 2) {                        // q (pre-scaled) / k: f16 [n][d]
        f16* oh = ((p == 0) ? qh : kh) + hboff + (size_t)n_glob * 64;
        #pragma unroll
        for (int t = 0; t < 2; ++t) {
            const f16v& oc = t ? o1 : o0;
            #pragma unroll
            for (int g = 0; g < 4; ++g) {
                int d0 = 8 * g + 4 * lh + 32 * t;
                h4v hv;
                hv.x = (f16)oc[4 * g + 0]; hv.y = (f16)oc[4 * g + 1];
                hv.z = (f16)oc[4 * g + 2]; hv.w = (f16)oc[4 * g + 3];
                *(h4v*)(oh + d0) = hv;
            }
        }
    } else {                            // v: transposed [d][n]
        f16* oh = vth + hboff;
        #pragma unroll
        for (int t = 0; t < 2; ++t) {
            const f16v& oc = t ? o1 : o0;
            #pragma unroll
            for (int r = 0; r < 16; ++r) {
                int d = (r & 3) + 8 * (r >> 2) + 4 * lh + 32 * t;
                oh[(size_t)d * NTOK + n_glob] = (f16)oc[r];
            }
        }
    }
}

// ---------------------------------------------------------------------------
// attn_mfma: f16 flash attention, K-SPLIT x2, dual-Q, XCD-aware 1D grid.
// UNCHANGED (77.3 us; five structural variants r5/7/9/10/12 all land
// 75-77 us -> practical floor of this decomposition).
// 2-wave fully-resident blocks + r7 B1/B2 barrier schedule.
// ---------------------------------------------------------------------------
__global__ __launch_bounds__(128, 2) void attn_mfma(
    const f16* __restrict__ qh, const f16* __restrict__ kh,
    const f16* __restrict__ vth, f16* __restrict__ wsth)
{
    const int bid   = blockIdx.x;     // 0..1151
    const int xcd   = bid & 7;
    const int slot  = bid >> 3;       // 0..143
    const int hb    = xcd * 4 + (slot / 36);
    const int rtile = slot % 36;      // 64-row tile
    const int h_    = hb >> 2, b = hb & 3;
    const int tid   = threadIdx.x;
    const int w     = tid >> 6;       // wave 0..1  (= k-tile parity stream)
    const int lane  = tid & 63;
    const int lm    = lane & 31;
    const int lh    = lane >> 5;

    // [K/V][parity=w][row][col] = exactly 32 KiB -> 5 blocks/CU capacity
    __shared__ __align__(16) f16 SMEM[2][2][64][64];

    const size_t hboff = (size_t)hb * HBSTRIDE;
    const int mA = rtile * 64 + lm;              // q-row, set A
    const int mB = mA + 32;                      // q-row, set B

    h8v QfA[4], QfB[4];
    #pragma unroll
    for (int s = 0; s < 4; ++s) {
        QfA[s] = *(const h8v*)(qh + hboff + (size_t)mA * 64 + (2 * s + lh) * 8);
        QfB[s] = *(const h8v*)(qh + hboff + (size_t)mB * 64 + (2 * s + lh) * 8);
    }

    f16v oA0, oA1, oB0, oB1;
    #pragma unroll
    for (int i = 0; i < 16; ++i) { oA0[i] = 0.f; oA1[i] = 0.f; oB0[i] = 0.f; oB1[i] = 0.f; }
    float lsumA = 0.f, lsumB = 0.f;

    const f16* kb = kh + hboff;
    const f16* vb = vth + hboff;

    // Each wave stages its OWN parity tile; LDS dest linear, source column
    // pre-swizzled so reads use slot c ^ (row&7).
    auto stageK = [&](int t) {
        const int kts = 2 * t + w;
        f16* dst = &SMEM[0][w][0][0];
        #pragma unroll
        for (int i = 0; i < 8; ++i) {
            int g = i * 64 + lane; int row = g >> 3; int c = (g & 7) ^ (row & 7);
            GLOAD_LDS(kb + kts * 4096 + row * 64 + c * 8, dst + i * 512);
        }
    };
    auto stageV = [&](int t) {
        const int kts = 2 * t + w;
        f16* dst = &SMEM[1][w][0][0];
        #pragma unroll
        for (int i = 0; i < 8; ++i) {
            int g = i * 64 + lane; int row = g >> 3; int c = (g & 7) ^ (row & 7);
            GLOAD_LDS(vb + (size_t)row * 2304 + kts * 64 + c * 8, dst + i * 512);
        }
    };

    stageK(0);
    __syncthreads();                   // K(0) drained + synced
    stageV(0);                         // flies under QK(0), drained at B1(0)

    for (int st = 0; st < 18; ++st) {
        // ---- QK^T from K[w]
        f16v sA0, sA1, sB0, sB1;
        #pragma unroll
        for (int i = 0; i < 16; ++i) {
            sA0[i] = -PBIAS; sA1[i] = -PBIAS; sB0[i] = -PBIAS; sB1[i] = -PBIAS;
        }

        __builtin_amdgcn_s_setprio(1);
        #pragma unroll
        for (int s = 0; s < 4; ++s) {
            const int p = ((2 * s + lh) ^ (lm & 7)) * 8;
            h8v k0 = *(const h8v*)&SMEM[0][w][lm][p];
            h8v k1 = *(const h8v*)&SMEM[0][w][lm + 32][p];
            sA0 = __builtin_amdgcn_mfma_f32_32x32x16_f16(k0, QfA[s], sA0, 0, 0, 0);
            sA1 = __builtin_amdgcn_mfma_f32_32x32x16_f16(k1, QfA[s], sA1, 0, 0, 0);
            sB0 = __builtin_amdgcn_mfma_f32_32x32x16_f16(k0, QfB[s], sB0, 0, 0, 0);
            sB1 = __builtin_amdgcn_mfma_f32_32x32x16_f16(k1, QfB[s], sB1, 0, 0, 0);
        }
        __builtin_amdgcn_s_setprio(0);

        __syncthreads();               // B1: drains V(st) DMA; K reads done
        if (st + 1 < 18) stageK(st + 1);   // flies under SM+PV

        // ---- softmax: exp2 + 4-way partial-sum trees
        float pa0 = 0.f, pa1 = 0.f, pa2 = 0.f, pa3 = 0.f;
        float pb0 = 0.f, pb1 = 0.f, pb2 = 0.f, pb3 = 0.f;
        #pragma unroll
        for (int i = 0; i < 16; i += 4) {
            sA0[i+0] = EXP2(sA0[i+0]); pa0 += sA0[i+0];
            sA0[i+1] = EXP2(sA0[i+1]); pa1 += sA0[i+1];
            sA0[i+2] = EXP2(sA0[i+2]); pa2 += sA0[i+2];
            sA0[i+3] = EXP2(sA0[i+3]); pa3 += sA0[i+3];
        }
        #pragma unroll
        for (int i = 0; i < 16; i += 4) {
            sA1[i+0] = EXP2(sA1[i+0]); pa0 += sA1[i+0];
            sA1[i+1] = EXP2(sA1[i+1]); pa1 += sA1[i+1];
            sA1[i+2] = EXP2(sA1[i+2]); pa2 += sA1[i+2];
            sA1[i+3] = EXP2(sA1[i+3]); pa3 += sA1[i+3];
        }
        #pragma unroll
        for (int i = 0; i < 16; i += 4) {
            sB0[i+0] = EXP2(sB0[i+0]); pb0 += sB0[i+0];
            sB0[i+1] = EXP2(sB0[i+1]); pb1 += sB0[i+1];
            sB0[i+2] = EXP2(sB0[i+2]); pb2 += sB0[i+2];
            sB0[i+3] = EXP2(sB0[i+3]); pb3 += sB0[i+3];
        }
        #pragma unroll
        for (int i = 0; i < 16; i += 4) {
            sB1[i+0] = EXP2(sB1[i+0]); pb0 += sB1[i+0];
            sB1[i+1] = EXP2(sB1[i+1]); pb1 += sB1[i+1];
            sB1[i+2] = EXP2(sB1[i+2]); pb2 += sB1[i+2];
            sB1[i+3] = EXP2(sB1[i+3]); pb3 += sB1[i+3];
        }
        lsumA += (pa0 + pa1) + (pa2 + pa3);
        lsumB += (pb0 + pb1) + (pb2 + pb3);

        // pack + redistribute (VALU, verified round-5)
        h8v pfA[4], pfB[4];
        #pragma unroll
        for (int s = 0; s < 4; ++s) {
            const int q2 = 8 * (s & 1);
            const f16v& ja = (s >> 1) ? sA1 : sA0;
            const f16v& jb = (s >> 1) ? sB1 : sB0;
            uint a0 = pk2(ja[q2 + 0], ja[q2 + 1]);
            uint a1 = pk2(ja[q2 + 2], ja[q2 + 3]);
            uint a2 = pk2(ja[q2 + 4], ja[q2 + 5]);
            uint a3 = pk2(ja[q2 + 6], ja[q2 + 7]);
            auto a02 = __builtin_amdgcn_permlane32_swap(a0, a2, false, false);
            auto a13 = __builtin_amdgcn_permlane32_swap(a1, a3, false, false);
            uint4 ua = { a02[0], a13[0], a02[1], a13[1] };
            pfA[s] = __builtin_bit_cast(h8v, ua);
            uint b0 = pk2(jb[q2 + 0], jb[q2 + 1]);
            uint b1 = pk2(jb[q2 + 2], jb[q2 + 3]);
            uint b2 = pk2(jb[q2 + 4], jb[q2 + 5]);
            uint b3 = pk2(jb[q2 + 6], jb[q2 + 7]);
            auto b02 = __builtin_amdgcn_permlane32_swap(b0, b2, false, false);
            auto b13 = __builtin_amdgcn_permlane32_swap(b1, b3, false, false);
            uint4 ub = { b02[0], b13[0], b02[1], b13[1] };
            pfB[s] = __builtin_bit_cast(h8v, ub);
        }

        // ---- PV from V[w] (drained at B1)
        __builtin_amdgcn_s_setprio(1);
        #pragma unroll
        for (int s = 0; s < 4; ++s) {
            const int p = ((2 * s + lh) ^ (lm & 7)) * 8;
            h8v v0 = *(const h8v*)&SMEM[1][w][lm][p];
            h8v v1 = *(const h8v*)&SMEM[1][w][lm + 32][p];
            oA0 = __builtin_amdgcn_mfma_f32_32x32x16_f16(v0, pfA[s], oA0, 0, 0, 0);
            oA1 = __builtin_amdgcn_mfma_f32_32x32x16_f16(v1, pfA[s], oA1, 0, 0, 0);
            oB0 = __builtin_amdgcn_mfma_f32_32x32x16_f16(v0, pfB[s], oB0, 0, 0, 0);
            oB1 = __builtin_amdgcn_mfma_f32_32x32x16_f16(v1, pfB[s], oB1, 0, 0, 0);
        }
        __builtin_amdgcn_s_setprio(0);

        __syncthreads();               // B2: drains K(st+1); V reads done
        if (st + 1 < 18) stageV(st + 1);   // flies under next QK
    }

    // K-split reduction. RED[64][65] fp32 (pad-65 -> conflict-free) + lsum
    // array, aliased into dead SMEM (17.2 KB of 32 KB). Loop's final B2
    // guarantees all SMEM reads are done before these writes.
    float* red  = (float*)&SMEM[0][0][0][0];
    float* lred = red + 64 * 65;
    if (w == 1) {
        float* d = red + (size_t)lane * 65;
        #pragma unroll
        for (int i = 0; i < 16; ++i) {
            d[i]      = oA0[i]; d[16 + i] = oA1[i];
            d[32 + i] = oB0[i]; d[48 + i] = oB1[i];
        }
        lred[2 * lane]     = lsumA;
        lred[2 * lane + 1] = lsumB;
    }
    __syncthreads();
    if (w == 0) {
        const float* sp = red + (size_t)lane * 65;
        #pragma unroll
        for (int i = 0; i < 16; ++i) {
            oA0[i] += sp[i];      oA1[i] += sp[16 + i];
            oB0[i] += sp[32 + i]; oB1[i] += sp[48 + i];
        }
        lsumA += lred[2 * lane];
        lsumB += lred[2 * lane + 1];
        lsumA += __shfl_xor(lsumA, 32);
        lsumB += __shfl_xor(lsumB, 32);
        float invA = 1.0f / lsumA, invB = 1.0f / lsumB;

        f16* wrA = wsth + ((size_t)h_ * NTOK + mA) * 256 + b * 64;
        f16* wrB = wsth + ((size_t)h_ * NTOK + mB) * 256 + b * 64;
        #pragma unroll
        for (int g = 0; g < 4; ++g) {
            h4v r0, r1;
            r0.x = (f16)(oA0[4 * g + 0] * invA); r0.y = (f16)(oA0[4 * g + 1] * invA);
            r0.z = (f16)(oA0[4 * g + 2] * invA); r0.w = (f16)(oA0[4 * g + 3] * invA);
            *(h4v*)(wrA + 8 * g + 4 * lh) = r0;
            r1.x = (f16)(oA1[4 * g + 0] * invA); r1.y = (f16)(oA1[4 * g + 1] * invA);
            r1.z = (f16)(oA1[4 * g + 2] * invA); r1.w = (f16)(oA1[4 * g + 3] * invA);
            *(h4v*)(wrA + 32 + 8 * g + 4 * lh) = r1;
        }
        #pragma unroll
        for (int g = 0; g < 4; ++g) {
            h4v r0, r1;
            r0.x = (f16)(oB0[4 * g + 0] * invB); r0.y = (f16)(oB0[4 * g + 1] * invB);
            r0.z = (f16)(oB0[4 * g + 2] * invB); r0.w = (f16)(oB0[4 * g + 3] * invB);
            *(h4v*)(wrB + 8 * g + 4 * lh) = r0;
            r1.x = (f16)(oB1[4 * g + 0] * invB); r1.y = (f16)(oB1[4 * g + 1] * invB);
            r1.z = (f16)(oB1[4 * g + 2] * invB); r1.w = (f16)(oB1[4 * g + 3] * invB);
            *(h4v*)(wrB + 32 + 8 * g + 4 * lh) = r1;
        }
    }
}

// ---------------------------------------------------------------------------
// outconv_mfma: out[b][o][n] = Wo[o][ch]*ws[b][ch][n], single-f16 MFMA.
// Unchanged.
// ---------------------------------------------------------------------------
__global__ __launch_bounds__(128) void outconv_mfma(
    const f16* __restrict__ woc, const f16* __restrict__ ws,
    float* __restrict__ out)
{
    const int ntile = blockIdx.x;
    const int otile = blockIdx.y;
    const int b     = blockIdx.z;

    __shared__ __align__(16) f16 Wos[2][64][64];
    __shared__ __align__(16) f16 Xs[2][64][72];

    const int tid = threadIdx.x;
    const int w = tid >> 6, lane = tid & 63;
    const int lm = lane & 31, lh = lane >> 5;
    const int n_loc  = w * 32 + lm;
    const int n_glob = ntile * 64 + n_loc;
    const int pr = tid >> 2;          // ch pair 0..31
    const int qn = tid & 3;           // n quarter (16 n)

    const f16* Wb = woc + (size_t)(otile * 64) * 512;
    const f16* wsb = ws + (size_t)b * 512 * NTOK + ntile * 64 + qn * 16;

    auto stageW = [&](int buf, int c0) {    // 8 DMAs split across 2 waves
        #pragma unroll
        for (int j = 0; j < 4; ++j) {
            int i = w * 4 + j;
            int g = i * 64 + lane; int row = g >> 3; int c = (g & 7) ^ (row & 7);
            GLOAD_LDS(Wb + (size_t)row * 512 + c0 + c * 8,
                      &Wos[buf][0][0] + i * 512);
        }
    };

    uint4 x0, x1, x2, x3;                   // named scalars: promoted, no spill
    auto loadB = [&](int c0) {
        const f16* r0 = wsb + (size_t)(c0 + 2 * pr) * NTOK;
        const f16* r1 = r0 + NTOK;
        x0 = *(const uint4*)(r0);
        x1 = *(const uint4*)(r0 + 8);
        x2 = *(const uint4*)(r1);
        x3 = *(const uint4*)(r1 + 8);
    };
    auto storeB = [&](int buf) {
        us8 a0 = __builtin_bit_cast(us8, x0), a1 = __builtin_bit_cast(us8, x1);
        us8 b0 = __builtin_bit_cast(us8, x2), b1 = __builtin_bit_cast(us8, x3);
        #pragma unroll
        for (int j = 0; j < 8; ++j) {
            *(uint*)&Xs[buf][qn * 16 + j][2 * pr]     = (uint)a0[j] | ((uint)b0[j] << 16);
            *(uint*)&Xs[buf][qn * 16 + 8 + j][2 * pr] = (uint)a1[j] | ((uint)b1[j] << 16);
        }
    };

    f16v o0, o1;
    #pragma unroll
    for (int i = 0; i < 16; ++i) { o0[i] = 0.f; o1[i] = 0.f; }

    stageW(0, 0);
    loadB(0);
    storeB(0);
    for (int c0 = 0; c0 < 512; c0 += 64) {
        const int cur = (c0 >> 6) & 1;
        __syncthreads();                    // DMA drained, Xs[cur] visible
        if (c0 + 64 < 512) { stageW(cur ^ 1, c0 + 64); loadB(c0 + 64); }
        #pragma unroll
        for (int s = 0; s < 4; ++s) {
            const int pp = ((2 * s + lh) ^ (lm & 7)) * 8;   // swizzled W slot
            const int co = (2 * s + lh) * 8;                // padded X slot
            h8v a0 = *(const h8v*)&Wos[cur][lm][pp];
            h8v a1 = *(const h8v*)&Wos[cur][lm + 32][pp];
            h8v bh = *(const h8v*)&Xs[cur][n_loc][co];
            o0 = __builtin_amdgcn_mfma_f32_32x32x16_f16(a0, bh, o0, 0, 0, 0);
            o1 = __builtin_amdgcn_mfma_f32_32x32x16_f16(a1, bh, o1, 0, 0, 0);
        }
        if (c0 + 64 < 512) storeB(cur ^ 1);
    }

    #pragma unroll
    for (int t = 0; t < 2; ++t) {
        const f16v& oc = t ? o1 : o0;
        #pragma unroll
        for (int r = 0; r < 16; ++r) {
            int orow = otile * 64 + (r & 3) + 8 * (r >> 2) + 4 * lh + 32 * t;
            out[((size_t)b * CIN + orow) * NTOK + n_glob] = oc[r];
        }
    }
}

// ---------------------------------------------------------------------------
// MEASUREMENT ROUND: prep/proj/outconv are idempotent (pure input->output,
// no accumulation), so duplicating each launch adds exactly one kernel-wall
// to the total while preserving correctness. Readout: S = new_total - 169.5
// = prep + proj + outconv combined wall. Pre-committed interpretation:
//   S < 25  -> fixed overhead dominates non-attn budget -> revert + declare
//   25-45   -> kernels small; <=20 us headroom even if halved
//   S > 45  -> kernel walls dominate; target largest next round
// ---------------------------------------------------------------------------
extern "C" void kernel_launch(void* const* d_in, const int* in_sizes, int n_in,
                              void* d_out, int out_size, void* d_ws, size_t ws_size,
                              hipStream_t stream)
{
    const float* x  = (const float*)d_in[0];
    const float* Wq = (const float*)d_in[1];
    const float* Wk = (const float*)d_in[2];
    const float* Wv = (const float*)d_in[3];
    const float* Wo = (const float*)d_in[4];
    float* out = (float*)d_out;

    // Workspace (f16; aliases time-disjoint):
    f16* qh   = (f16*)d_ws;
    f16* kh   = qh   + QKV_ELEMS;
    f16* vth  = kh   + QKV_ELEMS;
    f16* wsth = vth  + QKV_ELEMS;      // attn output, f16 [h][n][b][d]
    f16* xt   = wsth;                  // alias (dead before attn writes wsth)
    f16* wc   = wsth + QKV_ELEMS;      // pre-cast weights (single f16)
    f16* woc  = wc   + 3 * WSZ;

    prep<<<dim3(1088), 256, 0, stream>>>(x, Wq, Wk, Wv, Wo, wc, woc, xt);
    prep<<<dim3(1088), 256, 0, stream>>>(x, Wq, Wk, Wv, Wo, wc, woc, xt);      // DUP
    proj_mfma<<<dim3(36, 24, 4), 128, 0, stream>>>(wc, xt, qh, kh, vth);
    proj_mfma<<<dim3(36, 24, 4), 128, 0, stream>>>(wc, xt, qh, kh, vth);       // DUP
    attn_mfma<<<dim3(1152), 128, 0, stream>>>(qh, kh, vth, wsth);
    outconv_mfma<<<dim3(36, 4, 4), 128, 0, stream>>>(woc, wsth, out);
    outconv_mfma<<<dim3(36, 4, 4), 128, 0, stream>>>(woc, wsth, out);          // DUP
}

// Round 16
// 166.836 us; speedup vs baseline: 1.2233x; 1.2233x over previous
//
#include <hip/hip_runtime.h>

// Problem constants
#define B_     4
#define CIN    256
#define NTOK   2304        // 48*48
#define HEADS  8
#define HD     64
#define SCALE  0.125f      // 1/sqrt(64)
#define LOG2E  1.44269504088896f
#define QSCALE (SCALE * LOG2E)     // fold softmax exp->exp2 conversion into q
#define PBIAS  4.0f                // static softmax normalizer, folded into acc init
#define QKV_ELEMS (HEADS * B_ * NTOK * HD)   // 4,718,592
#define HBSTRIDE 147456    // 2304*64 elems per (h,b)
#define WSZ    131072      // elems in one of Wq/Wk/Wv ([8][64][256]) and Wo ([256][512])

typedef _Float16 f16;
typedef _Float16 __attribute__((ext_vector_type(8))) h8v;   // MFMA A/B frag
typedef _Float16 __attribute__((ext_vector_type(4))) h4v;
typedef ushort   __attribute__((ext_vector_type(8))) us8;
typedef float    __attribute__((ext_vector_type(16))) f16v; // 32x32 MFMA acc

__device__ inline uint pk2(float a, float b) { // pack 2xf32 -> 2xf16 (RTZ)
    auto v = __builtin_amdgcn_cvt_pkrtz(a, b);
    return __builtin_bit_cast(uint, v);
}
#define EXP2(x) __builtin_amdgcn_exp2f(x)      // native v_exp_f32

// async global->LDS DMA, 16 B/lane, LDS dest = uniform base + lane*16
#define GLOAD_LDS(g, l) __builtin_amdgcn_global_load_lds( \
    (const __attribute__((address_space(1))) unsigned int*)(g), \
    (__attribute__((address_space(3))) unsigned int*)(l), 16, 0, 0)

// ---------------------------------------------------------------------------
// prep: fused castw + tcastf (data-independent; saves one launch).
// Blocks 0..511:   weights fp32 -> f16 (QSCALE folded into Wq).
// Blocks 512..1087: x fp32 [b][C][NTOK] -> xt f16 TRANSPOSED [b][n][C].
// ---------------------------------------------------------------------------
__global__ __launch_bounds__(256) void prep(
    const float* __restrict__ x,
    const float* __restrict__ Wq, const float* __restrict__ Wk,
    const float* __restrict__ Wv, const float* __restrict__ Wo,
    f16* __restrict__ wc, f16* __restrict__ woc, f16* __restrict__ xt)
{
    __shared__ float T[64][65];
    const int bid = blockIdx.x;
    const int tid = threadIdx.x;

    if (bid < 512) {                       // ---- castw path
        int e4 = (bid * 256 + tid) * 4;
        const float* src; f16* dst; float mult = 1.0f; int off;
        if (e4 < WSZ)          { src = Wq; off = e4;           dst = wc;           mult = QSCALE; }
        else if (e4 < 2 * WSZ) { src = Wk; off = e4 - WSZ;     dst = wc + WSZ; }
        else if (e4 < 3 * WSZ) { src = Wv; off = e4 - 2 * WSZ; dst = wc + 2 * WSZ; }
        else                   { src = Wo; off = e4 - 3 * WSZ; dst = woc; }
        float4 r = *(const float4*)(src + off);
        h4v hv;
        hv.x = (f16)(r.x * mult); hv.y = (f16)(r.y * mult);
        hv.z = (f16)(r.z * mult); hv.w = (f16)(r.w * mult);
        *(h4v*)(dst + off) = hv;
        return;
    }

    // ---- tcastf path
    const int r  = bid - 512;              // 0..575
    const int n0 = (r % 36) * 64;
    const int c0 = ((r / 36) % 4) * 64;
    const int b  = r / 144;
    const float* sb = x + ((size_t)b * CIN + c0) * NTOK;
    #pragma unroll
    for (int i = 0; i < 16; ++i) {
        int idx = tid + 256 * i;
        int rr = idx >> 6, ll = idx & 63;
        T[ll][rr] = sb[(size_t)rr * NTOK + n0 + ll];
    }
    __syncthreads();
    const size_t ob = ((size_t)b * NTOK + n0) * CIN + c0;
    #pragma unroll
    for (int i = 0; i < 4; ++i) {
        int idx = tid + 256 * i;
        int row = idx >> 4, c4 = (idx & 15) * 4;
        h4v v;
        v.x = (f16)T[row][c4 + 0]; v.y = (f16)T[row][c4 + 1];
        v.z = (f16)T[row][c4 + 2]; v.w = (f16)T[row][c4 + 3];
        *(h4v*)(xt + ob + (size_t)row * CIN + c4) = v;
    }
}

// ---------------------------------------------------------------------------
// proj_mfma: q/k/v projections, single-f16 MFMA. 32 KiB single-buffered
// LDS (5 blocks/CU), conservative compute->B->stage->B schedule. Block 128
// (2 waves): wave0 DMAs W, wave1 DMAs X. Grid (36, 24, 4).
// ---------------------------------------------------------------------------
__global__ __launch_bounds__(128) void proj_mfma(
    const f16* __restrict__ wc, const f16* __restrict__ xt,
    f16* __restrict__ qh, f16* __restrict__ kh, f16* __restrict__ vth)
{
    const int ntile = blockIdx.x;
    const int hp    = blockIdx.y;
    const int b     = blockIdx.z;
    const int p     = hp >> 3, h = hp & 7;
    const int hb    = h * 4 + b;
    const f16* Wp = wc + ((size_t)p * 8 + h) * (HD * CIN);

    // swizzled: physical slot c of row r holds logical col-slot c ^ (r&7)
    __shared__ __align__(16) f16 Ws[64][64], Xs[64][64];   // 32 KiB

    const int tid = threadIdx.x;
    const int w = tid >> 6, lane = tid & 63;
    const int lm = lane & 31, lh = lane >> 5;
    const int n_loc  = w * 32 + lm;
    const int n_glob = ntile * 64 + n_loc;

    const f16* xb = xt + ((size_t)b * NTOK + ntile * 64) * CIN;

    auto stage = [&](int c0) {
        const f16* src = (w == 0) ? Wp : xb;
        f16* dst = (w == 0) ? &Ws[0][0] : &Xs[0][0];
        #pragma unroll
        for (int i = 0; i < 8; ++i) {
            int g = i * 64 + lane; int row = g >> 3; int c = (g & 7) ^ (row & 7);
            GLOAD_LDS(src + (size_t)row * CIN + c0 + c * 8, dst + i * 512);
        }
    };

    f16v o0, o1;
    #pragma unroll
    for (int i = 0; i < 16; ++i) { o0[i] = 0.f; o1[i] = 0.f; }

    stage(0);
    __syncthreads();                       // drain chunk 0
    for (int c0 = 0; c0 < CIN; c0 += 64) {
        #pragma unroll
        for (int s = 0; s < 4; ++s) {
            const int pp = ((2 * s + lh) ^ (lm & 7)) * 8;   // (lm+32)&7 == lm&7
            h8v a0 = *(const h8v*)&Ws[lm][pp];
            h8v a1 = *(const h8v*)&Ws[lm + 32][pp];
            h8v bh = *(const h8v*)&Xs[n_loc][pp];           // n_loc&7 == lm&7
            o0 = __builtin_amdgcn_mfma_f32_32x32x16_f16(a0, bh, o0, 0, 0, 0);
            o1 = __builtin_amdgcn_mfma_f32_32x32x16_f16(a1, bh, o1, 0, 0, 0);
        }
        if (c0 + 64 < CIN) {
            __syncthreads();               // all reads of this chunk done
            stage(c0 + 64);
            __syncthreads();               // drain next chunk
        }
    }

    const size_t hboff = (size_t)hb * HBSTRIDE;
    if (p < 2) {                        // q (pre-scaled) / k: f16 [n][d]
        f16* oh = ((p == 0) ? qh : kh) + hboff + (size_t)n_glob * 64;
        #pragma unroll
        for (int t = 0; t < 2; ++t) {
            const f16v& oc = t ? o1 : o0;
            #pragma unroll
            for (int g = 0; g < 4; ++g) {
                int d0 = 8 * g + 4 * lh + 32 * t;
                h4v hv;
                hv.x = (f16)oc[4 * g + 0]; hv.y = (f16)oc[4 * g + 1];
                hv.z = (f16)oc[4 * g + 2]; hv.w = (f16)oc[4 * g + 3];
                *(h4v*)(oh + d0) = hv;
            }
        }
    } else {                            // v: transposed [d][n]
        f16* oh = vth + hboff;
        #pragma unroll
        for (int t = 0; t < 2; ++t) {
            const f16v& oc = t ? o1 : o0;
            #pragma unroll
            for (int r = 0; r < 16; ++r) {
                int d = (r & 3) + 8 * (r >> 2) + 4 * lh + 32 * t;
                oh[(size_t)d * NTOK + n_glob] = (f16)oc[r];
            }
        }
    }
}

// ---------------------------------------------------------------------------
// attn_mfma: f16 flash attention, K-SPLIT x2, dual-Q, XCD-aware 1D grid.
// FINAL FORM (77.3 us; five structural variants r5/7/9/10/12 all land
// 75-77.5 us -> practical floor of this decomposition: phase-serialized
// QK->SM->PV whose pipelined variants exceed the 128-VGPR budget).
// 2-wave fully-resident blocks + r7 B1/B2 barrier schedule.
// ---------------------------------------------------------------------------
__global__ __launch_bounds__(128, 2) void attn_mfma(
    const f16* __restrict__ qh, const f16* __restrict__ kh,
    const f16* __restrict__ vth, f16* __restrict__ wsth)
{
    const int bid   = blockIdx.x;     // 0..1151
    const int xcd   = bid & 7;
    const int slot  = bid >> 3;       // 0..143
    const int hb    = xcd * 4 + (slot / 36);
    const int rtile = slot % 36;      // 64-row tile
    const int h_    = hb >> 2, b = hb & 3;
    const int tid   = threadIdx.x;
    const int w     = tid >> 6;       // wave 0..1  (= k-tile parity stream)
    const int lane  = tid & 63;
    const int lm    = lane & 31;
    const int lh    = lane >> 5;

    // [K/V][parity=w][row][col] = exactly 32 KiB -> 5 blocks/CU capacity
    __shared__ __align__(16) f16 SMEM[2][2][64][64];

    const size_t hboff = (size_t)hb * HBSTRIDE;
    const int mA = rtile * 64 + lm;              // q-row, set A
    const int mB = mA + 32;                      // q-row, set B

    h8v QfA[4], QfB[4];
    #pragma unroll
    for (int s = 0; s < 4; ++s) {
        QfA[s] = *(const h8v*)(qh + hboff + (size_t)mA * 64 + (2 * s + lh) * 8);
        QfB[s] = *(const h8v*)(qh + hboff + (size_t)mB * 64 + (2 * s + lh) * 8);
    }

    f16v oA0, oA1, oB0, oB1;
    #pragma unroll
    for (int i = 0; i < 16; ++i) { oA0[i] = 0.f; oA1[i] = 0.f; oB0[i] = 0.f; oB1[i] = 0.f; }
    float lsumA = 0.f, lsumB = 0.f;

    const f16* kb = kh + hboff;
    const f16* vb = vth + hboff;

    // Each wave stages its OWN parity tile; LDS dest linear, source column
    // pre-swizzled so reads use slot c ^ (row&7).
    auto stageK = [&](int t) {
        const int kts = 2 * t + w;
        f16* dst = &SMEM[0][w][0][0];
        #pragma unroll
        for (int i = 0; i < 8; ++i) {
            int g = i * 64 + lane; int row = g >> 3; int c = (g & 7) ^ (row & 7);
            GLOAD_LDS(kb + kts * 4096 + row * 64 + c * 8, dst + i * 512);
        }
    };
    auto stageV = [&](int t) {
        const int kts = 2 * t + w;
        f16* dst = &SMEM[1][w][0][0];
        #pragma unroll
        for (int i = 0; i < 8; ++i) {
            int g = i * 64 + lane; int row = g >> 3; int c = (g & 7) ^ (row & 7);
            GLOAD_LDS(vb + (size_t)row * 2304 + kts * 64 + c * 8, dst + i * 512);
        }
    };

    stageK(0);
    __syncthreads();                   // K(0) drained + synced
    stageV(0);                         // flies under QK(0), drained at B1(0)

    for (int st = 0; st < 18; ++st) {
        // ---- QK^T from K[w]
        f16v sA0, sA1, sB0, sB1;
        #pragma unroll
        for (int i = 0; i < 16; ++i) {
            sA0[i] = -PBIAS; sA1[i] = -PBIAS; sB0[i] = -PBIAS; sB1[i] = -PBIAS;
        }

        __builtin_amdgcn_s_setprio(1);
        #pragma unroll
        for (int s = 0; s < 4; ++s) {
            const int p = ((2 * s + lh) ^ (lm & 7)) * 8;
            h8v k0 = *(const h8v*)&SMEM[0][w][lm][p];
            h8v k1 = *(const h8v*)&SMEM[0][w][lm + 32][p];
            sA0 = __builtin_amdgcn_mfma_f32_32x32x16_f16(k0, QfA[s], sA0, 0, 0, 0);
            sA1 = __builtin_amdgcn_mfma_f32_32x32x16_f16(k1, QfA[s], sA1, 0, 0, 0);
            sB0 = __builtin_amdgcn_mfma_f32_32x32x16_f16(k0, QfB[s], sB0, 0, 0, 0);
            sB1 = __builtin_amdgcn_mfma_f32_32x32x16_f16(k1, QfB[s], sB1, 0, 0, 0);
        }
        __builtin_amdgcn_s_setprio(0);

        __syncthreads();               // B1: drains V(st) DMA; K reads done
        if (st + 1 < 18) stageK(st + 1);   // flies under SM+PV

        // ---- softmax: exp2 + 4-way partial-sum trees
        float pa0 = 0.f, pa1 = 0.f, pa2 = 0.f, pa3 = 0.f;
        float pb0 = 0.f, pb1 = 0.f, pb2 = 0.f, pb3 = 0.f;
        #pragma unroll
        for (int i = 0; i < 16; i += 4) {
            sA0[i+0] = EXP2(sA0[i+0]); pa0 += sA0[i+0];
            sA0[i+1] = EXP2(sA0[i+1]); pa1 += sA0[i+1];
            sA0[i+2] = EXP2(sA0[i+2]); pa2 += sA0[i+2];
            sA0[i+3] = EXP2(sA0[i+3]); pa3 += sA0[i+3];
        }
        #pragma unroll
        for (int i = 0; i < 16; i += 4) {
            sA1[i+0] = EXP2(sA1[i+0]); pa0 += sA1[i+0];
            sA1[i+1] = EXP2(sA1[i+1]); pa1 += sA1[i+1];
            sA1[i+2] = EXP2(sA1[i+2]); pa2 += sA1[i+2];
            sA1[i+3] = EXP2(sA1[i+3]); pa3 += sA1[i+3];
        }
        #pragma unroll
        for (int i = 0; i < 16; i += 4) {
            sB0[i+0] = EXP2(sB0[i+0]); pb0 += sB0[i+0];
            sB0[i+1] = EXP2(sB0[i+1]); pb1 += sB0[i+1];
            sB0[i+2] = EXP2(sB0[i+2]); pb2 += sB0[i+2];
            sB0[i+3] = EXP2(sB0[i+3]); pb3 += sB0[i+3];
        }
        #pragma unroll
        for (int i = 0; i < 16; i += 4) {
            sB1[i+0] = EXP2(sB1[i+0]); pb0 += sB1[i+0];
            sB1[i+1] = EXP2(sB1[i+1]); pb1 += sB1[i+1];
            sB1[i+2] = EXP2(sB1[i+2]); pb2 += sB1[i+2];
            sB1[i+3] = EXP2(sB1[i+3]); pb3 += sB1[i+3];
        }
        lsumA += (pa0 + pa1) + (pa2 + pa3);
        lsumB += (pb0 + pb1) + (pb2 + pb3);

        // pack + redistribute (VALU, verified round-5)
        h8v pfA[4], pfB[4];
        #pragma unroll
        for (int s = 0; s < 4; ++s) {
            const int q2 = 8 * (s & 1);
            const f16v& ja = (s >> 1) ? sA1 : sA0;
            const f16v& jb = (s >> 1) ? sB1 : sB0;
            uint a0 = pk2(ja[q2 + 0], ja[q2 + 1]);
            uint a1 = pk2(ja[q2 + 2], ja[q2 + 3]);
            uint a2 = pk2(ja[q2 + 4], ja[q2 + 5]);
            uint a3 = pk2(ja[q2 + 6], ja[q2 + 7]);
            auto a02 = __builtin_amdgcn_permlane32_swap(a0, a2, false, false);
            auto a13 = __builtin_amdgcn_permlane32_swap(a1, a3, false, false);
            uint4 ua = { a02[0], a13[0], a02[1], a13[1] };
            pfA[s] = __builtin_bit_cast(h8v, ua);
            uint b0 = pk2(jb[q2 + 0], jb[q2 + 1]);
            uint b1 = pk2(jb[q2 + 2], jb[q2 + 3]);
            uint b2 = pk2(jb[q2 + 4], jb[q2 + 5]);
            uint b3 = pk2(jb[q2 + 6], jb[q2 + 7]);
            auto b02 = __builtin_amdgcn_permlane32_swap(b0, b2, false, false);
            auto b13 = __builtin_amdgcn_permlane32_swap(b1, b3, false, false);
            uint4 ub = { b02[0], b13[0], b02[1], b13[1] };
            pfB[s] = __builtin_bit_cast(h8v, ub);
        }

        // ---- PV from V[w] (drained at B1)
        __builtin_amdgcn_s_setprio(1);
        #pragma unroll
        for (int s = 0; s < 4; ++s) {
            const int p = ((2 * s + lh) ^ (lm & 7)) * 8;
            h8v v0 = *(const h8v*)&SMEM[1][w][lm][p];
            h8v v1 = *(const h8v*)&SMEM[1][w][lm + 32][p];
            oA0 = __builtin_amdgcn_mfma_f32_32x32x16_f16(v0, pfA[s], oA0, 0, 0, 0);
            oA1 = __builtin_amdgcn_mfma_f32_32x32x16_f16(v1, pfA[s], oA1, 0, 0, 0);
            oB0 = __builtin_amdgcn_mfma_f32_32x32x16_f16(v0, pfB[s], oB0, 0, 0, 0);
            oB1 = __builtin_amdgcn_mfma_f32_32x32x16_f16(v1, pfB[s], oB1, 0, 0, 0);
        }
        __builtin_amdgcn_s_setprio(0);

        __syncthreads();               // B2: drains K(st+1); V reads done
        if (st + 1 < 18) stageV(st + 1);   // flies under next QK
    }

    // K-split reduction. RED[64][65] fp32 (pad-65 -> conflict-free) + lsum
    // array, aliased into dead SMEM (17.2 KB of 32 KB). Loop's final B2
    // guarantees all SMEM reads are done before these writes.
    float* red  = (float*)&SMEM[0][0][0][0];
    float* lred = red + 64 * 65;
    if (w == 1) {
        float* d = red + (size_t)lane * 65;
        #pragma unroll
        for (int i = 0; i < 16; ++i) {
            d[i]      = oA0[i]; d[16 + i] = oA1[i];
            d[32 + i] = oB0[i]; d[48 + i] = oB1[i];
        }
        lred[2 * lane]     = lsumA;
        lred[2 * lane + 1] = lsumB;
    }
    __syncthreads();
    if (w == 0) {
        const float* sp = red + (size_t)lane * 65;
        #pragma unroll
        for (int i = 0; i < 16; ++i) {
            oA0[i] += sp[i];      oA1[i] += sp[16 + i];
            oB0[i] += sp[32 + i]; oB1[i] += sp[48 + i];
        }
        lsumA += lred[2 * lane];
        lsumB += lred[2 * lane + 1];
        lsumA += __shfl_xor(lsumA, 32);
        lsumB += __shfl_xor(lsumB, 32);
        float invA = 1.0f / lsumA, invB = 1.0f / lsumB;

        f16* wrA = wsth + ((size_t)h_ * NTOK + mA) * 256 + b * 64;
        f16* wrB = wsth + ((size_t)h_ * NTOK + mB) * 256 + b * 64;
        #pragma unroll
        for (int g = 0; g < 4; ++g) {
            h4v r0, r1;
            r0.x = (f16)(oA0[4 * g + 0] * invA); r0.y = (f16)(oA0[4 * g + 1] * invA);
            r0.z = (f16)(oA0[4 * g + 2] * invA); r0.w = (f16)(oA0[4 * g + 3] * invA);
            *(h4v*)(wrA + 8 * g + 4 * lh) = r0;
            r1.x = (f16)(oA1[4 * g + 0] * invA); r1.y = (f16)(oA1[4 * g + 1] * invA);
            r1.z = (f16)(oA1[4 * g + 2] * invA); r1.w = (f16)(oA1[4 * g + 3] * invA);
            *(h4v*)(wrA + 32 + 8 * g + 4 * lh) = r1;
        }
        #pragma unroll
        for (int g = 0; g < 4; ++g) {
            h4v r0, r1;
            r0.x = (f16)(oB0[4 * g + 0] * invB); r0.y = (f16)(oB0[4 * g + 1] * invB);
            r0.z = (f16)(oB0[4 * g + 2] * invB); r0.w = (f16)(oB0[4 * g + 3] * invB);
            *(h4v*)(wrB + 8 * g + 4 * lh) = r0;
            r1.x = (f16)(oB1[4 * g + 0] * invB); r1.y = (f16)(oB1[4 * g + 1] * invB);
            r1.z = (f16)(oB1[4 * g + 2] * invB); r1.w = (f16)(oB1[4 * g + 3] * invB);
            *(h4v*)(wrB + 32 + 8 * g + 4 * lh) = r1;
        }
    }
}

// ---------------------------------------------------------------------------
// outconv_mfma: out[b][o][n] = Wo[o][ch]*ws[b][ch][n], single-f16 MFMA.
// Wo via DMA (dbuf, swizzled, split across both waves); B fused-transpose
// staged via 4 NAMED uint4 scalars. Single barrier per chunk. Grid (36,4,4).
// ---------------------------------------------------------------------------
__global__ __launch_bounds__(128) void outconv_mfma(
    const f16* __restrict__ woc, const f16* __restrict__ ws,
    float* __restrict__ out)
{
    const int ntile = blockIdx.x;
    const int otile = blockIdx.y;
    const int b     = blockIdx.z;

    __shared__ __align__(16) f16 Wos[2][64][64];
    __shared__ __align__(16) f16 Xs[2][64][72];

    const int tid = threadIdx.x;
    const int w = tid >> 6, lane = tid & 63;
    const int lm = lane & 31, lh = lane >> 5;
    const int n_loc  = w * 32 + lm;
    const int n_glob = ntile * 64 + n_loc;
    const int pr = tid >> 2;          // ch pair 0..31
    const int qn = tid & 3;           // n quarter (16 n)

    const f16* Wb = woc + (size_t)(otile * 64) * 512;
    const f16* wsb = ws + (size_t)b * 512 * NTOK + ntile * 64 + qn * 16;

    auto stageW = [&](int buf, int c0) {    // 8 DMAs split across 2 waves
        #pragma unroll
        for (int j = 0; j < 4; ++j) {
            int i = w * 4 + j;
            int g = i * 64 + lane; int row = g >> 3; int c = (g & 7) ^ (row & 7);
            GLOAD_LDS(Wb + (size_t)row * 512 + c0 + c * 8,
                      &Wos[buf][0][0] + i * 512);
        }
    };

    uint4 x0, x1, x2, x3;                   // named scalars: promoted, no spill
    auto loadB = [&](int c0) {
        const f16* r0 = wsb + (size_t)(c0 + 2 * pr) * NTOK;
        const f16* r1 = r0 + NTOK;
        x0 = *(const uint4*)(r0);
        x1 = *(const uint4*)(r0 + 8);
        x2 = *(const uint4*)(r1);
        x3 = *(const uint4*)(r1 + 8);
    };
    auto storeB = [&](int buf) {
        us8 a0 = __builtin_bit_cast(us8, x0), a1 = __builtin_bit_cast(us8, x1);
        us8 b0 = __builtin_bit_cast(us8, x2), b1 = __builtin_bit_cast(us8, x3);
        #pragma unroll
        for (int j = 0; j < 8; ++j) {
            *(uint*)&Xs[buf][qn * 16 + j][2 * pr]     = (uint)a0[j] | ((uint)b0[j] << 16);
            *(uint*)&Xs[buf][qn * 16 + 8 + j][2 * pr] = (uint)a1[j] | ((uint)b1[j] << 16);
        }
    };

    f16v o0, o1;
    #pragma unroll
    for (int i = 0; i < 16; ++i) { o0[i] = 0.f; o1[i] = 0.f; }

    stageW(0, 0);
    loadB(0);
    storeB(0);
    for (int c0 = 0; c0 < 512; c0 += 64) {
        const int cur = (c0 >> 6) & 1;
        __syncthreads();                    // DMA drained, Xs[cur] visible
        if (c0 + 64 < 512) { stageW(cur ^ 1, c0 + 64); loadB(c0 + 64); }
        #pragma unroll
        for (int s = 0; s < 4; ++s) {
            const int pp = ((2 * s + lh) ^ (lm & 7)) * 8;   // swizzled W slot
            const int co = (2 * s + lh) * 8;                // padded X slot
            h8v a0 = *(const h8v*)&Wos[cur][lm][pp];
            h8v a1 = *(const h8v*)&Wos[cur][lm + 32][pp];
            h8v bh = *(const h8v*)&Xs[cur][n_loc][co];
            o0 = __builtin_amdgcn_mfma_f32_32x32x16_f16(a0, bh, o0, 0, 0, 0);
            o1 = __builtin_amdgcn_mfma_f32_32x32x16_f16(a1, bh, o1, 0, 0, 0);
        }
        if (c0 + 64 < 512) storeB(cur ^ 1);
    }

    #pragma unroll
    for (int t = 0; t < 2; ++t) {
        const f16v& oc = t ? o1 : o0;
        #pragma unroll
        for (int r = 0; r < 16; ++r) {
            int orow = otile * 64 + (r & 3) + 8 * (r >> 2) + 4 * lh + 32 * t;
            out[((size_t)b * CIN + orow) * NTOK + n_glob] = oc[r];
        }
    }
}

// ---------------------------------------------------------------------------
extern "C" void kernel_launch(void* const* d_in, const int* in_sizes, int n_in,
                              void* d_out, int out_size, void* d_ws, size_t ws_size,
                              hipStream_t stream)
{
    const float* x  = (const float*)d_in[0];
    const float* Wq = (const float*)d_in[1];
    const float* Wk = (const float*)d_in[2];
    const float* Wv = (const float*)d_in[3];
    const float* Wo = (const float*)d_in[4];
    float* out = (float*)d_out;

    // Workspace (f16; aliases time-disjoint):
    f16* qh   = (f16*)d_ws;
    f16* kh   = qh   + QKV_ELEMS;
    f16* vth  = kh   + QKV_ELEMS;
    f16* wsth = vth  + QKV_ELEMS;      // attn output, f16 [h][n][b][d]
    f16* xt   = wsth;                  // alias (dead before attn writes wsth)
    f16* wc   = wsth + QKV_ELEMS;      // pre-cast weights (single f16)
    f16* woc  = wc   + 3 * WSZ;

    prep<<<dim3(1088), 256, 0, stream>>>(x, Wq, Wk, Wv, Wo, wc, woc, xt);
    proj_mfma<<<dim3(36, 24, 4), 128, 0, stream>>>(wc, xt, qh, kh, vth);
    attn_mfma<<<dim3(1152), 128, 0, stream>>>(qh, kh, vth, wsth);
    outconv_mfma<<<dim3(36, 4, 4), 128, 0, stream>>>(woc, wsth, out);
}